// Round 9
// baseline (230.198 us; speedup 1.0000x reference)
//
#include <hip/hip_runtime.h>
#include <math.h>

// z: [32,64,64,64] (B,C,H,W)  N = B*H*W = 131072 locations, C = 64
// E: [512,64]
// out (fp32 flat): loss(1) | z_q(8388608) | perp(1) | enc(67108864) | idx(131072)
#define OUT_ZQ   1LL
#define OUT_PERP 8388609LL
#define OUT_ENC  8388610LL
#define OUT_IDX  75497474LL

// ws (2.1 KB): [0..511] hist(int) | [512..513] u64 fixed-point loss accumulator
#define WS_HIST   0
#define WS_LOSS64 512
#define LOSS_SCALE 16777216.0   // 2^24

__global__ void vq_init(float* __restrict__ ws) {
  int t = threadIdx.x;  // 512 threads
  ((int*)ws)[WS_HIST + t] = 0;
  if (t == 0) *((unsigned long long*)(ws + WS_LOSS64)) = 0ull;
}

// Fused: np-replicated argmin + idx + hist + one-hot + z_q + loss.
// Block = 256 threads = 4 waves = ONE row (64 locations) x 4 j-quarters.
// Grid = 2048 blocks -> 8192 waves -> up to 8 waves/SIMD (latency hiding).
// d_j = fl( fl(zsum + esum_j) - fl(2*mm_j) ); mm_j = sequential-k fp32 FMA chain;
// zsum/esum = numpy pairwise (8 accumulators). First-min: strict < ascending j
// within wave; quarter merge in ascending-q order with strict <.
__global__ __launch_bounds__(256, 4) void vq_fused(const float* __restrict__ z,
                                                   const float* __restrict__ E,
                                                   float* __restrict__ ws,
                                                   float* __restrict__ out) {
#pragma clang fp contract(off)
  const int tid  = threadIdx.x;
  const int lane = tid & 63;
  const int jq   = __builtin_amdgcn_readfirstlane(tid >> 6);  // 0..3
  const int jbase = jq * 128;
  const int row = blockIdx.x;            // 0..2047 (= b*64 + h)
  const int b = row >> 6, h = row & 63;
  const size_t zbase = (size_t)b * 262144 + (size_t)h * 64;

  // esum_j in LDS (numpy pairwise over fl(e^2); contract off). 2 j's per thread.
  __shared__ float s_esum[512];
  for (int j = tid; j < 512; j += 256) {
    const float* e = E + j * 64;
    float q0 = e[0]*e[0], q1 = e[1]*e[1], q2 = e[2]*e[2], q3 = e[3]*e[3];
    float q4 = e[4]*e[4], q5 = e[5]*e[5], q6 = e[6]*e[6], q7 = e[7]*e[7];
#pragma unroll
    for (int i = 8; i < 64; i += 8) {
      q0 += e[i+0]*e[i+0]; q1 += e[i+1]*e[i+1];
      q2 += e[i+2]*e[i+2]; q3 += e[i+3]*e[i+3];
      q4 += e[i+4]*e[i+4]; q5 += e[i+5]*e[i+5];
      q6 += e[i+6]*e[i+6]; q7 += e[i+7]*e[i+7];
    }
    s_esum[j] = ((q0 + q1) + (q2 + q3)) + ((q4 + q5) + (q6 + q7));
  }

  // lane w holds its location's 64-dim vector (all 4 waves: same row, L1-hot)
  float zf[64];
#pragma unroll
  for (int c = 0; c < 64; ++c)
    zf[c] = z[zbase + (size_t)c * 4096 + lane];

  // zsum: numpy pairwise over fl(z^2)
  float q0 = zf[0]*zf[0], q1 = zf[1]*zf[1], q2 = zf[2]*zf[2], q3 = zf[3]*zf[3];
  float q4 = zf[4]*zf[4], q5 = zf[5]*zf[5], q6 = zf[6]*zf[6], q7 = zf[7]*zf[7];
#pragma unroll
  for (int i = 8; i < 64; i += 8) {
    q0 += zf[i+0]*zf[i+0]; q1 += zf[i+1]*zf[i+1];
    q2 += zf[i+2]*zf[i+2]; q3 += zf[i+3]*zf[i+3];
    q4 += zf[i+4]*zf[i+4]; q5 += zf[i+5]*zf[i+5];
    q6 += zf[i+6]*zf[i+6]; q7 += zf[i+7]*zf[i+7];
  }
  const float zsum = ((q0 + q1) + (q2 + q3)) + ((q4 + q5) + (q6 + q7));
  __syncthreads();  // s_esum ready

  // scan this wave's 128-j quarter
  float best = 1e30f; int bi = 0;
  const float* __restrict__ Ej = E + (size_t)jbase * 64;
  for (int jj = 0; jj < 128; jj += 4) {
    const float* __restrict__ e0 = Ej + jj * 64;  // wave-uniform -> s_load
    const float* __restrict__ e1 = e0 + 64;
    const float* __restrict__ e2 = e0 + 128;
    const float* __restrict__ e3 = e0 + 192;
    float a0 = 0.f, a1 = 0.f, a2 = 0.f, a3 = 0.f;
#pragma unroll
    for (int c = 0; c < 64; ++c) {   // sequential-k fused-FMA chain (BLAS-like)
      a0 = fmaf(zf[c], e0[c], a0);
      a1 = fmaf(zf[c], e1[c], a1);
      a2 = fmaf(zf[c], e2[c], a2);
      a3 = fmaf(zf[c], e3[c], a3);
    }
    const int j = jbase + jj;
    float d0 = (zsum + s_esum[j    ]) - 2.0f * a0;
    float d1 = (zsum + s_esum[j + 1]) - 2.0f * a1;
    float d2 = (zsum + s_esum[j + 2]) - 2.0f * a2;
    float d3 = (zsum + s_esum[j + 3]) - 2.0f * a3;
    if (d0 < best) { best = d0; bi = j;     }
    if (d1 < best) { best = d1; bi = j + 1; }
    if (d2 < best) { best = d2; bi = j + 2; }
    if (d3 < best) { best = d3; bi = j + 3; }
  }

  // merge quarters (ascending q, strict < -> global first-min)
  __shared__ float s_d[4][64];
  __shared__ int   s_i[4][64];
  __shared__ int   s_idx[64];
  s_d[jq][lane] = best;
  s_i[jq][lane] = bi;
  __syncthreads();
  if (jq == 0) {
#pragma unroll
    for (int q = 1; q < 4; ++q) {
      float dq = s_d[q][lane];
      int   iq = s_i[q][lane];
      if (dq < best) { best = dq; bi = iq; }
    }
    s_idx[lane] = bi;
    out[OUT_IDX + (size_t)row * 64 + lane] = (float)bi;
    atomicAdd(&((int*)ws)[WS_HIST + bi], 1);
  }
  __syncthreads();

  // one-hot: this row's 64 locations x 512 floats = 128 KB contiguous (float2)
  {
    float2* enc = (float2*)(out + OUT_ENC + (size_t)row * 32768);
    const int o = tid * 2;
    for (int i = 0; i < 64; ++i) {
      int p = s_idx[i];
      float2 v;
      v.x = (o     == p) ? 1.f : 0.f;
      v.y = (o + 1 == p) ? 1.f : 0.f;
      enc[(size_t)i * 256 + tid] = v;
    }
  }

  // z_q + loss: wave 0 (zf in registers)
  if (jq == 0) {
    float lsum = 0.f;
    const int p = s_idx[lane];
    const float* Ep = E + (size_t)p * 64;   // per-lane gather, L1/L2-hot
#pragma unroll
    for (int c = 0; c < 64; ++c) {
      float ev = Ep[c];
      float d = ev - zf[c];
      lsum = fmaf(d, d, lsum);
      out[OUT_ZQ + zbase + (size_t)c * 4096 + lane] = ev;  // 256B/instr coalesced
    }
    for (int off = 32; off; off >>= 1) lsum += __shfl_down(lsum, off);
    if (lane == 0) {
      // deterministic: integer adds commute; 2^-24 quantization ~1e-11 on loss
      unsigned long long fx = (unsigned long long)((double)lsum * LOSS_SCALE);
      atomicAdd((unsigned long long*)(ws + WS_LOSS64), fx);
    }
  }
}

__global__ void vq_final(const float* __restrict__ ws, float* __restrict__ out) {
  int j = threadIdx.x; // 512
  const int* hist = (const int*)ws + WS_HIST;
  float p = (float)hist[j] * (1.f / 131072.f);
  float t = -p * logf(p + 1e-10f);
  for (int off = 32; off; off >>= 1) t += __shfl_down(t, off);
  __shared__ float st[8];
  int wv = j >> 6, ln = j & 63;
  if (ln == 0) st[wv] = t;
  __syncthreads();
  if (j == 0) {
    float e = 0.f;
#pragma unroll
    for (int i = 0; i < 8; ++i) e += st[i];
    out[OUT_PERP] = expf(e);
    double ls = (double)*((const unsigned long long*)(ws + WS_LOSS64)) * (1.0 / LOSS_SCALE);
    out[0] = (float)(ls * (1.25 / 8388608.0));
  }
}

extern "C" void kernel_launch(void* const* d_in, const int* in_sizes, int n_in,
                              void* d_out, int out_size, void* d_ws, size_t ws_size,
                              hipStream_t stream) {
  const float* z = (const float*)d_in[0];
  const float* E = (const float*)d_in[1];
  float* out = (float*)d_out;
  float* ws  = (float*)d_ws;
  vq_init<<<1, 512, 0, stream>>>(ws);
  vq_fused<<<2048, 256, 0, stream>>>(z, E, ws, out);
  vq_final<<<1, 512, 0, stream>>>(ws, out);
}

// Round 10
// 143.350 us; speedup vs baseline: 1.6058x; 1.6058x over previous
//
#include <hip/hip_runtime.h>
#include <math.h>

// z: [32,64,64,64] (B,C,H,W)  N = B*H*W = 131072 locations, C = 64
// E: [512,64]
// out (fp32 flat): loss(1) | z_q(8388608) | perp(1) | enc(67108864) | idx(131072)
#define OUT_ZQ   1LL
#define OUT_PERP 8388609LL
#define OUT_ENC  8388610LL
#define OUT_IDX  75497474LL

// ws: [0..511] hist(int) | [512..513] u64 fixed-point loss accumulator (proven R9)
#define WS_HIST   0
#define WS_LOSS64 512
#define LOSS_SCALE 16777216.0   // 2^24

typedef __attribute__((ext_vector_type(8))) short bf16x8;
typedef __attribute__((ext_vector_type(4))) float f32x4;

__device__ __forceinline__ unsigned short f2bf(float f) {  // RNE float->bf16
  unsigned u = __builtin_bit_cast(unsigned, f);
  u += 0x7FFFu + ((u >> 16) & 1u);
  return (unsigned short)(u >> 16);
}

__global__ void vq_init(float* __restrict__ ws) {
  int t = threadIdx.x;  // 512
  ((int*)ws)[WS_HIST + t] = 0;
  if (t == 0) *((unsigned long long*)(ws + WS_LOSS64)) = 0ull;
}

// One block = 64 locations (one (b,h) row). 4 waves, each owning 128 j (8 n-tiles).
// MFMA 16x16x32 bf16 scorer -> per-location qmin -> margin flag -> exact np-replica
// recheck of candidates (bit-identical to R5's passing arithmetic) -> outputs.
__global__ __launch_bounds__(256, 2) void vq_main(const float* __restrict__ z,
                                                  const float* __restrict__ E,
                                                  float* __restrict__ ws,
                                                  float* __restrict__ out) {
#pragma clang fp contract(off)
  const int tid  = threadIdx.x;
  const int lane = tid & 63;
  const int wv   = __builtin_amdgcn_readfirstlane(tid >> 6);
  const int g    = lane >> 4;     // 16-lane group
  const int ln16 = lane & 15;
  const int row  = blockIdx.x;    // 0..2047
  const int b = row >> 6, h = row & 63;
  const size_t zbase = (size_t)b * 262144 + (size_t)h * 64;

  __shared__ float lds_z[64][65];   // [w][c], stride 65: conflict-free
  __shared__ float s_esum[512];
  __shared__ float s_zsum[64];
  __shared__ float s_qpart[4][64];
  __shared__ float s_qthr[64];
  __shared__ int   s_cnt[64];
  __shared__ int   s_cand[64][12];
  __shared__ float s_dcand[64][12];
  __shared__ int   s_ovf[64];
  __shared__ int   s_idx[64];

  // ---- stage z tile (coalesced: lane=w, wave=c-quarter) ----
  for (int k = 0; k < 16; ++k) {
    int c = k * 4 + wv;
    lds_z[lane][c] = z[zbase + (size_t)c * 4096 + lane];
  }
  // ---- exact esum_j: numpy pairwise over fl(e^2) (proven pattern) ----
  for (int j = tid; j < 512; j += 256) {
    const float* e = E + j * 64;
    float q0=e[0]*e[0],q1=e[1]*e[1],q2=e[2]*e[2],q3=e[3]*e[3];
    float q4=e[4]*e[4],q5=e[5]*e[5],q6=e[6]*e[6],q7=e[7]*e[7];
#pragma unroll
    for (int i = 8; i < 64; i += 8) {
      q0+=e[i+0]*e[i+0]; q1+=e[i+1]*e[i+1]; q2+=e[i+2]*e[i+2]; q3+=e[i+3]*e[i+3];
      q4+=e[i+4]*e[i+4]; q5+=e[i+5]*e[i+5]; q6+=e[i+6]*e[i+6]; q7+=e[i+7]*e[i+7];
    }
    s_esum[j] = ((q0+q1)+(q2+q3))+((q4+q5)+(q6+q7));
  }
  if (tid < 64) { s_cnt[tid] = 0; s_ovf[tid] = 0; }
  __syncthreads();

  // ---- exact zsum per location: numpy pairwise over fl(z^2) ----
  if (tid < 64) {
    const float* zl = &lds_z[tid][0];
    float q0=zl[0]*zl[0],q1=zl[1]*zl[1],q2=zl[2]*zl[2],q3=zl[3]*zl[3];
    float q4=zl[4]*zl[4],q5=zl[5]*zl[5],q6=zl[6]*zl[6],q7=zl[7]*zl[7];
#pragma unroll
    for (int i = 8; i < 64; i += 8) {
      q0+=zl[i+0]*zl[i+0]; q1+=zl[i+1]*zl[i+1]; q2+=zl[i+2]*zl[i+2]; q3+=zl[i+3]*zl[i+3];
      q4+=zl[i+4]*zl[i+4]; q5+=zl[i+5]*zl[i+5]; q6+=zl[i+6]*zl[i+6]; q7+=zl[i+7]*zl[i+7];
    }
    s_zsum[tid] = ((q0+q1)+(q2+q3))+((q4+q5)+(q6+q7));
  }

  // ---- build B-frags: this wave's 8 n-tiles (j range wv*128..+128) ----
  // layout (tr_b16-derived): lane holds n=ln16, k = kk*32 + 16*(i>>2) + 4*g + (i&3)
  bf16x8 Bf[8][2];
#pragma unroll
  for (int t = 0; t < 8; ++t) {
    int j = (wv * 8 + t) * 16 + ln16;
    const float* ej = E + (size_t)j * 64;
#pragma unroll
    for (int kk = 0; kk < 2; ++kk) {
      int c0 = kk * 32 + 4 * g;
      bf16x8 v;
#pragma unroll
      for (int i = 0; i < 4; ++i) v[i]     = (short)f2bf(ej[c0 + i]);
#pragma unroll
      for (int i = 0; i < 4; ++i) v[4 + i] = (short)f2bf(ej[c0 + 16 + i]);
      Bf[t][kk] = v;
    }
  }
  // ---- build A-frags: all 4 m-tiles (lane holds m=mt*16+ln16, same k pattern) ----
  bf16x8 Af[4][2];
#pragma unroll
  for (int mt = 0; mt < 4; ++mt) {
    int m = mt * 16 + ln16;
#pragma unroll
    for (int kk = 0; kk < 2; ++kk) {
      int c0 = kk * 32 + 4 * g;
      bf16x8 v;
#pragma unroll
      for (int i = 0; i < 4; ++i) v[i]     = (short)f2bf(lds_z[m][c0 + i]);
#pragma unroll
      for (int i = 0; i < 4; ++i) v[4 + i] = (short)f2bf(lds_z[m][c0 + 16 + i]);
      Af[mt][kk] = v;
    }
  }

  // ---- pass A: qmin per location ----
  float qmin[4][4];
#pragma unroll
  for (int mt = 0; mt < 4; ++mt)
#pragma unroll
    for (int r = 0; r < 4; ++r) qmin[mt][r] = 1e30f;
#pragma unroll
  for (int mt = 0; mt < 4; ++mt) {
#pragma unroll
    for (int t = 0; t < 8; ++t) {
      f32x4 C = {0.f, 0.f, 0.f, 0.f};
      C = __builtin_amdgcn_mfma_f32_16x16x32_bf16(Af[mt][0], Bf[t][0], C, 0, 0, 0);
      C = __builtin_amdgcn_mfma_f32_16x16x32_bf16(Af[mt][1], Bf[t][1], C, 0, 0, 0);
      float es = s_esum[(wv * 8 + t) * 16 + ln16];
#pragma unroll
      for (int r = 0; r < 4; ++r) {
        float q = es - 2.0f * C[r];
        qmin[mt][r] = fminf(qmin[mt][r], q);
      }
    }
  }
#pragma unroll
  for (int off = 1; off < 16; off <<= 1)
#pragma unroll
    for (int mt = 0; mt < 4; ++mt)
#pragma unroll
      for (int r = 0; r < 4; ++r)
        qmin[mt][r] = fminf(qmin[mt][r], __shfl_xor(qmin[mt][r], off));
  if (ln16 == 0)
#pragma unroll
    for (int mt = 0; mt < 4; ++mt)
#pragma unroll
      for (int r = 0; r < 4; ++r)
        s_qpart[wv][mt * 16 + g * 4 + r] = qmin[mt][r];
  __syncthreads();
  if (tid < 64) {
    float qm = fminf(fminf(s_qpart[0][tid], s_qpart[1][tid]),
                     fminf(s_qpart[2][tid], s_qpart[3][tid]));
    // rigorous margin: 2*(2u_bf16)*||z||*||e||max + slack; ||e|| <= sqrt(64)/512
    s_qthr[tid] = qm + (2.5e-4f * sqrtf(s_zsum[tid]) + 1e-4f);
  }
  __syncthreads();

  // ---- pass B: recompute scores (bit-identical), flag candidates ----
#pragma unroll
  for (int mt = 0; mt < 4; ++mt) {
#pragma unroll
    for (int t = 0; t < 8; ++t) {
      f32x4 C = {0.f, 0.f, 0.f, 0.f};
      C = __builtin_amdgcn_mfma_f32_16x16x32_bf16(Af[mt][0], Bf[t][0], C, 0, 0, 0);
      C = __builtin_amdgcn_mfma_f32_16x16x32_bf16(Af[mt][1], Bf[t][1], C, 0, 0, 0);
      int j = (wv * 8 + t) * 16 + ln16;
      float es = s_esum[j];
#pragma unroll
      for (int r = 0; r < 4; ++r) {
        float q = es - 2.0f * C[r];
        int m = mt * 16 + g * 4 + r;
        if (q <= s_qthr[m]) {
          int pos = atomicAdd(&s_cnt[m], 1);
          if (pos < 12) s_cand[m][pos] = j; else s_ovf[m] = 1;
        }
      }
    }
  }
  __syncthreads();

  // ---- phase C: exact np-replica d for candidates (R5 arithmetic verbatim) ----
  {
    const int m = tid & 63;
    const float* zl = &lds_z[m][0];
    int cnt = s_cnt[m]; if (cnt > 12) cnt = 12;
    for (int s = wv; s < cnt; s += 4) {
      int j = s_cand[m][s];
      const float* ej = E + (size_t)j * 64;
      float a = 0.f;
#pragma unroll
      for (int c = 0; c < 64; ++c) a = fmaf(zl[c], ej[c], a);
      s_dcand[m][s] = (s_zsum[m] + s_esum[j]) - 2.0f * a;
    }
  }
  __syncthreads();

  // ---- final select (first-min by (d, j)), idx + hist ----
  if (tid < 64) {
    const int m = tid;
    int cnt = s_cnt[m];
    int bi;
    if (cnt == 0 || cnt > 12 || s_ovf[m]) {
      // exact full scan fallback (provably rare)
      const float* zl = &lds_z[m][0];
      float bd = 1e30f; bi = 0;
      for (int j = 0; j < 512; ++j) {
        const float* ej = E + (size_t)j * 64;
        float a = 0.f;
        for (int c = 0; c < 64; ++c) a = fmaf(zl[c], ej[c], a);
        float d = (s_zsum[m] + s_esum[j]) - 2.0f * a;
        if (d < bd) { bd = d; bi = j; }
      }
    } else {
      float bd = 1e30f; bi = 1 << 30;
      for (int s = 0; s < cnt; ++s) {
        float d = s_dcand[m][s]; int j = s_cand[m][s];
        if (d < bd || (d == bd && j < bi)) { bd = d; bi = j; }
      }
    }
    s_idx[m] = bi;
    out[OUT_IDX + (size_t)row * 64 + m] = (float)bi;
    atomicAdd(&((int*)ws)[WS_HIST + bi], 1);
  }
  __syncthreads();

  // ---- one-hot: 64 rows x 512 floats = 128 KB contiguous (proven R9 pattern) ----
  {
    float2* enc = (float2*)(out + OUT_ENC + (size_t)row * 32768);
    const int o = tid * 2;
    for (int i = 0; i < 64; ++i) {
      int p = s_idx[i];
      float2 v;
      v.x = (o     == p) ? 1.f : 0.f;
      v.y = (o + 1 == p) ? 1.f : 0.f;
      enc[(size_t)i * 256 + tid] = v;
    }
  }

  // ---- z_q + loss (wave 0; zf from LDS) ----
  if (wv == 0) {
    float lsum = 0.f;
    const int p = s_idx[lane];
    const float* Ep = E + (size_t)p * 64;
#pragma unroll
    for (int c = 0; c < 64; ++c) {
      float ev = Ep[c];
      float d = ev - lds_z[lane][c];
      lsum = fmaf(d, d, lsum);
      out[OUT_ZQ + zbase + (size_t)c * 4096 + lane] = ev;
    }
    for (int off = 32; off; off >>= 1) lsum += __shfl_down(lsum, off);
    if (lane == 0) {
      unsigned long long fx = (unsigned long long)((double)lsum * LOSS_SCALE);
      atomicAdd((unsigned long long*)(ws + WS_LOSS64), fx);
    }
  }
}

__global__ void vq_final(const float* __restrict__ ws, float* __restrict__ out) {
  int j = threadIdx.x; // 512
  const int* hist = (const int*)ws + WS_HIST;
  float p = (float)hist[j] * (1.f / 131072.f);
  float t = -p * logf(p + 1e-10f);
  for (int off = 32; off; off >>= 1) t += __shfl_down(t, off);
  __shared__ float st[8];
  int wv = j >> 6, ln = j & 63;
  if (ln == 0) st[wv] = t;
  __syncthreads();
  if (j == 0) {
    float e = 0.f;
#pragma unroll
    for (int i = 0; i < 8; ++i) e += st[i];
    out[OUT_PERP] = expf(e);
    double ls = (double)*((const unsigned long long*)(ws + WS_LOSS64)) * (1.0 / LOSS_SCALE);
    out[0] = (float)(ls * (1.25 / 8388608.0));
  }
}

extern "C" void kernel_launch(void* const* d_in, const int* in_sizes, int n_in,
                              void* d_out, int out_size, void* d_ws, size_t ws_size,
                              hipStream_t stream) {
  const float* z = (const float*)d_in[0];
  const float* E = (const float*)d_in[1];
  float* out = (float*)d_out;
  float* ws  = (float*)d_ws;
  vq_init<<<1, 512, 0, stream>>>(ws);
  vq_main<<<2048, 256, 0, stream>>>(z, E, ws, out);
  vq_final<<<1, 512, 0, stream>>>(ws, out);
}